// Round 9
// baseline (30.835 us; speedup 1.0000x reference)
//
#include <hip/hip_runtime.h>

#define HH 48
#define WW 48
#define HW 2304   // 48*48
#define NB 8      // N
#define CB 4      // COLOR
#define TB 3      // RGB

// pred_img_i[b,n,t,y,x] = 0.25 * sum_c sum_s kw[b,n,s,t,y,x] *
//     sum_{i,j in KxK} c1[..cur_s+i..]*c2[..cur_s+j..] * F[c, y+i-3, x+j-3]
// s=0:K=7,cur=9  s=1:K=5,cur=4  s=2:K=3,cur=1  s=3:K=1,cur=0
//
// R9: fused kernel, float2 pixel-pair per thread + phased register structure.
// Block = 256 thr = 4 waves (wave c = color c) on a 128-px chunk of one (b,n,t).
// Phase1 bv2[16] -> phase2 row loop (fp[8] window shared by the px pair,
// masks recomputed per row to save VGPRs) -> phase3 a2[16]+kw, final dots.
// LDS c-reduce (float2), lanes 0..63 write pred_img_i as float2.
// R8 lesson: no memset/atomics — keep the small dependent mean_fb kernel.
// R5 lesson: no launch_bounds occupancy cap (spills). R3 lesson: float2 only
// works with the phased structure (peak live regs ~90, not ~130).
__global__ __launch_bounds__(256) void kconv_fused2(
    const float* __restrict__ frames,   // (4, 8, 4, 48, 48)
    const float* __restrict__ core,     // (4, 3072, 48, 48)  ch=((n*32+q)*4+c)*3+t
    const float* __restrict__ kw,       // (4, 8, 4, 3, 48, 48)
    float* __restrict__ out)            // pred_img_i (4, 8, 3, 48, 48)
{
    const int blk = blockIdx.x;          // 4*8*3*18 = 1728
    const int pc  = blk % (HW / 128);    // 128-px chunk, 18 per image
    int rem = blk / (HW / 128);
    const int t = rem % TB; rem /= TB;
    const int n = rem % NB;
    const int b = rem / NB;
    const int tix = threadIdx.x;         // 0..255
    const int c    = tix >> 6;           // wave id = color
    const int lane = tix & 63;
    const int pix0 = pc * 128 + lane * 2;   // even; pair on same row (48 even)
    const int x0 = pix0 % WW;
    const int y  = pix0 / WW;

    const float* cp = core + ((size_t)b * 3072 + (size_t)((n * 32) * CB + c) * 3 + t) * HW + pix0;

    // phase 1: column weights (float2 per q: this px pair)
    float2 bv[16];
    #pragma unroll
    for (int q = 0; q < 16; ++q)
        bv[q] = *(const float2*)(cp + (size_t)((q + 16) * 12) * HW);

    const float* fb = frames + ((size_t)(b * NB + n) * CB + c) * HW;

    // phase 2: per-row inner sums; fp[8] window shared by the two pixels
    float in7x[7], in7y[7], in5x[5], in5y[5], in3x[3], in3y[3];
    float f1x = 0.f, f1y = 0.f;
    #pragma unroll
    for (int i = 0; i < 7; ++i) {
        const int yy = y + i - 3;
        const float ymsk = ((yy >= 0) & (yy < HH)) ? 1.f : 0.f;
        const float* frow = fb + min(max(yy, 0), HH - 1) * WW;
        float fp[8];
        #pragma unroll
        for (int j = 0; j < 8; ++j) {
            const int xx = x0 + j - 3;
            const float xm = ((xx >= 0) & (xx < WW)) ? ymsk : 0.f;
            fp[j] = frow[min(max(xx, 0), WW - 1)] * xm;   // branchless zero-pad
        }
        float s7x = 0.f, s7y = 0.f;
        #pragma unroll
        for (int j = 0; j < 7; ++j) {
            s7x = fmaf(bv[9 + j].x, fp[j],     s7x);
            s7y = fmaf(bv[9 + j].y, fp[j + 1], s7y);
        }
        in7x[i] = s7x; in7y[i] = s7y;
        if (i >= 1 && i <= 5) {
            float s5x = 0.f, s5y = 0.f;
            #pragma unroll
            for (int j = 0; j < 5; ++j) {
                s5x = fmaf(bv[4 + j].x, fp[1 + j], s5x);
                s5y = fmaf(bv[4 + j].y, fp[2 + j], s5y);
            }
            in5x[i - 1] = s5x; in5y[i - 1] = s5y;
        }
        if (i >= 2 && i <= 4) {
            float s3x = 0.f, s3y = 0.f;
            #pragma unroll
            for (int j = 0; j < 3; ++j) {
                s3x = fmaf(bv[1 + j].x, fp[2 + j], s3x);
                s3y = fmaf(bv[1 + j].y, fp[3 + j], s3y);
            }
            in3x[i - 2] = s3x; in3y[i - 2] = s3y;
        }
        if (i == 3) { f1x = bv[0].x * fp[3]; f1y = bv[0].y * fp[4]; }
    }

    // keep a[]/kw loads out of phase 2 (peak-pressure control)
    __builtin_amdgcn_sched_barrier(0);

    // phase 3: row weights + kernel_weight, final dots
    float2 a[16];
    #pragma unroll
    for (int q = 0; q < 16; ++q)
        a[q] = *(const float2*)(cp + (size_t)(q * 12) * HW);

    const float* kwp = kw + ((size_t)(b * NB + n) * 12 + t) * HW + pix0;
    const float2 kw0 = *(const float2*)(kwp);
    const float2 kw1 = *(const float2*)(kwp + (size_t)3 * HW);
    const float2 kw2 = *(const float2*)(kwp + (size_t)6 * HW);
    const float2 kw3 = *(const float2*)(kwp + (size_t)9 * HW);

    float r7x = 0.f, r7y = 0.f, r5x = 0.f, r5y = 0.f, r3x = 0.f, r3y = 0.f;
    #pragma unroll
    for (int i = 0; i < 7; ++i) { r7x = fmaf(a[9 + i].x, in7x[i], r7x);
                                  r7y = fmaf(a[9 + i].y, in7y[i], r7y); }
    #pragma unroll
    for (int i = 0; i < 5; ++i) { r5x = fmaf(a[4 + i].x, in5x[i], r5x);
                                  r5y = fmaf(a[4 + i].y, in5y[i], r5y); }
    #pragma unroll
    for (int i = 0; i < 3; ++i) { r3x = fmaf(a[1 + i].x, in3x[i], r3x);
                                  r3y = fmaf(a[1 + i].y, in3y[i], r3y); }
    const float r1x = a[0].x * f1x;
    const float r1y = a[0].y * f1y;

    const float vx = fmaf(kw0.x, r7x, fmaf(kw1.x, r5x, fmaf(kw2.x, r3x, kw3.x * r1x)));
    const float vy = fmaf(kw0.y, r7y, fmaf(kw1.y, r5y, fmaf(kw2.y, r3y, kw3.y * r1y)));

    // LDS c-reduce (float2 lanes; 2-way bank aliasing = free)
    __shared__ float lds[CB][128];
    *(float2*)&lds[c][lane * 2] = make_float2(vx, vy);
    __syncthreads();
    if (tix < 64) {
        const float2 v0 = *(const float2*)&lds[0][tix * 2];
        const float2 v1 = *(const float2*)&lds[1][tix * 2];
        const float2 v2 = *(const float2*)&lds[2][tix * 2];
        const float2 v3 = *(const float2*)&lds[3][tix * 2];
        float2 s;
        s.x = 0.25f * (v0.x + v1.x + v2.x + v3.x);
        s.y = 0.25f * (v0.y + v1.y + v2.y + v3.y);
        *(float2*)&out[((size_t)(b * NB + n) * TB + t) * HW + pc * 128 + tix * 2] = s;
    }
}

// pred_img[b,t,pix] = mean_n pred_img_i[b,n,t,pix]
__global__ __launch_bounds__(256) void mean_fb(
    const float* __restrict__ pii, float* __restrict__ pm)
{
    const int tid = blockIdx.x * blockDim.x + threadIdx.x;  // 27648
    if (tid >= 4 * TB * HW) return;
    const int pix3 = tid % (TB * HW);
    const int b = tid / (TB * HW);
    float s = 0.f;
    #pragma unroll
    for (int n = 0; n < NB; ++n)
        s += pii[(size_t)((b * NB + n) * TB) * HW + pix3];
    pm[tid] = s * 0.125f;
}

extern "C" void kernel_launch(void* const* d_in, const int* in_sizes, int n_in,
                              void* d_out, int out_size, void* d_ws, size_t ws_size,
                              hipStream_t stream) {
    const float* frames = (const float*)d_in[0];
    const float* core   = (const float*)d_in[1];
    const float* kw     = (const float*)d_in[2];
    float* out = (float*)d_out;                  // pred_img_i: 221184 floats
    float* pm  = out + (size_t)4 * NB * TB * HW; // pred_img:   27648 floats

    kconv_fused2<<<4 * NB * TB * (HW / 128), 256, 0, stream>>>(frames, core, kw, out);
    mean_fb<<<(4 * TB * HW + 255) / 256, 256, 0, stream>>>(out, pm);
}